// Round 2
// baseline (248.886 us; speedup 1.0000x reference)
//
#include <hip/hip_runtime.h>
#include <hip/hip_bf16.h>
#include <math.h>

#define GN 12288
#define GE 196608
#define GK 1433
#define GC 32
#define BM 128

// ---------------- zero ----------------
__global__ void zero_kernel(unsigned* __restrict__ p, int n) {
    int i = blockIdx.x * blockDim.x + threadIdx.x;
    if (i < n) p[i] = 0u;
}

// ---------------- edge degree/count ----------------
__global__ void count_kernel(const int* __restrict__ ei,
                             unsigned* __restrict__ deg,
                             unsigned* __restrict__ cnt) {
    int e = blockIdx.x * blockDim.x + threadIdx.x;
    if (e < GE) {
        atomicAdd(&cnt[ei[e]], 1u);        // src
        atomicAdd(&deg[ei[GE + e]], 1u);   // dst
    }
}

// ---------------- prefix sum: 1024 threads x 12, wave shuffle scan ----------------
__global__ __launch_bounds__(1024) void prefix_kernel(const unsigned* __restrict__ cnt,
                                                      unsigned* __restrict__ offs) {
    __shared__ unsigned wsum[16];
    int t = threadIdx.x;
    int lane = t & 63, w = t >> 6;
    unsigned loc[12];
    unsigned s = 0;
    #pragma unroll
    for (int j = 0; j < 12; ++j) { loc[j] = cnt[t * 12 + j]; s += loc[j]; }
    // inclusive wave scan of s
    unsigned v = s;
    #pragma unroll
    for (int d = 1; d < 64; d <<= 1) {
        unsigned u = __shfl_up(v, d, 64);
        if (lane >= d) v += u;
    }
    if (lane == 63) wsum[w] = v;
    __syncthreads();
    if (t < 16) {
        unsigned ws_ = wsum[t];
        #pragma unroll
        for (int d = 1; d < 16; d <<= 1) {
            unsigned u = __shfl_up(ws_, d, 64);
            if (t >= d) ws_ += u;
        }
        wsum[t] = ws_;  // inclusive wave sums
    }
    __syncthreads();
    unsigned run = (w > 0 ? wsum[w - 1] : 0u) + (v - s);  // exclusive prefix of thread chunk
    #pragma unroll
    for (int j = 0; j < 12; ++j) { offs[t * 12 + j] = run; run += loc[j]; }
}

// ---------------- scatter into CSR ----------------
__global__ void scatter_kernel(const int* __restrict__ ei,
                               const unsigned* __restrict__ offs,
                               unsigned* __restrict__ cursor,
                               unsigned* __restrict__ adj) {
    int e = blockIdx.x * blockDim.x + threadIdx.x;
    if (e < GE) {
        int src = ei[e];
        unsigned pos = atomicAdd(&cursor[src], 1u);
        adj[offs[src] + pos] = (unsigned)ei[GE + e];
    }
}

// ---------------- GEMM: 1 row/thread, 32 accs, W via scalar loads ----------------
// LDS-pipe traffic ~1 ds_read_b32 per 32 FMA inst; W rows are wave-uniform -> s_load.
__global__ __launch_bounds__(128) void gemm_kernel(const float* __restrict__ x,
                                                   const float* __restrict__ W1,
                                                   float* __restrict__ partial,
                                                   int kchunk) {
    __shared__ float xs[BM * 33];  // pad 33: (t+kk)%32 banks, conflict-free
    int t = threadIdx.x;
    int row0 = blockIdx.x * BM;
    int ks = blockIdx.y;
    int k0 = ks * kchunk;
    int kend = min(GK, k0 + kchunk);
    float acc[32];
    #pragma unroll
    for (int c = 0; c < 32; ++c) acc[c] = 0.f;

    for (int kb = k0; kb < kend; kb += 32) {
        __syncthreads();
        #pragma unroll
        for (int l = 0; l < 32; ++l) {
            int idx = l * 128 + t;
            int r = idx >> 5, kk = idx & 31;
            int k = kb + kk;
            xs[r * 33 + kk] = (k < kend) ? x[(size_t)(row0 + r) * GK + k] : 0.f;
        }
        __syncthreads();
        #pragma unroll 2
        for (int kk = 0; kk < 32; ++kk) {
            float xv = xs[t * 33 + kk];
            int k = __builtin_amdgcn_readfirstlane(min(kb + kk, GK - 1));
            const float* __restrict__ wr = W1 + (size_t)k * GC;
            #pragma unroll
            for (int c = 0; c < 32; ++c) acc[c] = fmaf(xv, wr[c], acc[c]);
        }
    }
    float* po = partial + ((size_t)ks * GN + row0 + t) * GC;
    #pragma unroll
    for (int c = 0; c < 32; c += 4)
        *(float4*)(po + c) = make_float4(acc[c], acc[c + 1], acc[c + 2], acc[c + 3]);
}

// ---------------- reduce K-splits + precompute dis ----------------
__global__ void reduce_kernel(const float* __restrict__ partial, float* __restrict__ xw,
                              const unsigned* __restrict__ deg, float* __restrict__ dis,
                              int nsplit) {
    int i = blockIdx.x * blockDim.x + threadIdx.x;
    const size_t S = (size_t)GN * GC;
    float s = 0.f;
    for (int p = 0; p < nsplit; ++p) s += partial[p * S + i];
    xw[i] = s;
    if (i < GN) dis[i] = rsqrtf((float)(deg[i] + 1u));
}

// ---------------- GCN gather ----------------
__global__ __launch_bounds__(256) void gcn_kernel(const float* __restrict__ xw,
                                                  const float* __restrict__ dis,
                                                  const unsigned* __restrict__ cnt,
                                                  const unsigned* __restrict__ offs,
                                                  const unsigned* __restrict__ adj,
                                                  const float* __restrict__ b1,
                                                  float* __restrict__ h) {
    int w = threadIdx.x >> 6;
    int lane = threadIdx.x & 63;
    int i = blockIdx.x * 4 + w;
    int f = lane & 31, half = lane >> 5;
    unsigned ci = cnt[i], oi = offs[i];
    float acc = 0.f;
    for (unsigned j = half; j < ci; j += 2) {
        unsigned dst = adj[oi + j];
        acc += xw[(size_t)dst * GC + f] * dis[dst];
    }
    acc += __shfl_xor(acc, 32, 64);
    float disi = dis[i];
    float v = b1[f] + disi * (disi * xw[(size_t)i * GC + f] + acc);
    if (half == 0) h[(size_t)i * GC + f] = fmaxf(v, 0.f);
}

// ---------------- SAGE gather + fused head ----------------
__global__ __launch_bounds__(256) void sage_kernel(const float* __restrict__ h,
                                                   const unsigned* __restrict__ cnt,
                                                   const unsigned* __restrict__ offs,
                                                   const unsigned* __restrict__ adj,
                                                   const float* __restrict__ Wl,
                                                   const float* __restrict__ bl,
                                                   const float* __restrict__ Wr,
                                                   const float* __restrict__ br,
                                                   const float* __restrict__ W3,
                                                   const float* __restrict__ b3,
                                                   float* __restrict__ out) {
    __shared__ float sh[4][64];
    __shared__ float so[4][16];
    int w = threadIdx.x >> 6, lane = threadIdx.x & 63;
    int i = blockIdx.x * 4 + w;
    int f = lane & 31, half = lane >> 5;
    unsigned ci = cnt[i], oi = offs[i];
    float acc = 0.f;
    for (unsigned j = half; j < ci; j += 2) acc += h[(size_t)adj[oi + j] * GC + f];
    acc += __shfl_xor(acc, 32, 64);
    float agg = ci ? acc / (float)ci : 0.f;
    float hv = h[(size_t)i * GC + f];
    if (half == 0) { sh[w][f] = hv; sh[w][32 + f] = agg; }
    __syncthreads();
    int c = lane;
    float hid = 0.f;
    if (c < 16) {
        hid = bl[c] + br[c];
        #pragma unroll
        for (int ff = 0; ff < 32; ++ff)
            hid += sh[w][ff] * Wl[ff * 16 + c] + sh[w][32 + ff] * Wr[ff * 16 + c];
        hid = fmaxf(hid, 0.f);
    }
    float n2 = hid * hid;
    n2 += __shfl_xor(n2, 1, 64);
    n2 += __shfl_xor(n2, 2, 64);
    n2 += __shfl_xor(n2, 4, 64);
    n2 += __shfl_xor(n2, 8, 64);
    float o = hid / (sqrtf(n2) + 1e-6f);
    if (c < 16) so[w][c] = o;
    __syncthreads();
    float logit = -INFINITY;
    if (lane < 7) {
        logit = b3[lane];
        #pragma unroll
        for (int cc = 0; cc < 16; ++cc) logit += so[w][cc] * W3[cc * 7 + lane];
    }
    float m = logit;
    m = fmaxf(m, __shfl_xor(m, 1, 64));
    m = fmaxf(m, __shfl_xor(m, 2, 64));
    m = fmaxf(m, __shfl_xor(m, 4, 64));
    float e = expf(logit - m);
    float s = e;
    s += __shfl_xor(s, 1, 64);
    s += __shfl_xor(s, 2, 64);
    s += __shfl_xor(s, 4, 64);
    if (lane < 7) out[(size_t)i * 7 + lane] = e / s;
}

extern "C" void kernel_launch(void* const* d_in, const int* in_sizes, int n_in,
                              void* d_out, int out_size, void* d_ws, size_t ws_size,
                              hipStream_t stream) {
    const float* x  = (const float*)d_in[0];
    const int*   ei = (const int*)d_in[1];
    const float* W1 = (const float*)d_in[2];
    const float* b1 = (const float*)d_in[3];
    const float* Wl = (const float*)d_in[4];
    const float* bl = (const float*)d_in[5];
    const float* Wr = (const float*)d_in[6];
    const float* br = (const float*)d_in[7];
    const float* W3 = (const float*)d_in[8];
    const float* b3 = (const float*)d_in[9];
    float* out = (float*)d_out;

    // choose K-split count against ws capacity
    const size_t S = (size_t)GN * GC * 4;                 // 1.57 MB
    const size_t fixed = 2 * S + (size_t)GN * 4 * 5 + (size_t)GE * 4;
    int nsplit = (ws_size >= 12 * S + fixed) ? 12 : 4;
    int kchunk = (GK + nsplit - 1) / nsplit;

    char* ws = (char*)d_ws;
    float*    partial = (float*)(ws);
    float*    xw      = (float*)(ws + (size_t)nsplit * S);
    float*    h       = (float*)((char*)xw + S);
    float*    dis     = (float*)((char*)h + S);
    unsigned* deg     = (unsigned*)((char*)dis + (size_t)GN * 4);
    unsigned* cnt     = deg + GN;
    unsigned* cursor  = cnt + GN;
    unsigned* offs    = cursor + GN;
    unsigned* adj     = offs + GN;

    zero_kernel<<<(3 * GN + 255) / 256, 256, 0, stream>>>(deg, 3 * GN);
    count_kernel<<<GE / 256, 256, 0, stream>>>(ei, deg, cnt);
    prefix_kernel<<<1, 1024, 0, stream>>>(cnt, offs);
    scatter_kernel<<<GE / 256, 256, 0, stream>>>(ei, offs, cursor, adj);
    gemm_kernel<<<dim3(GN / BM, nsplit), 128, 0, stream>>>(x, W1, partial, kchunk);
    reduce_kernel<<<(GN * GC) / 256, 256, 0, stream>>>(partial, xw, deg, dis, nsplit);
    gcn_kernel<<<GN / 4, 256, 0, stream>>>(xw, dis, cnt, offs, adj, b1, h);
    sage_kernel<<<GN / 4, 256, 0, stream>>>(h, cnt, offs, adj, Wl, bl, Wr, br, W3, b3, out);
}

// Round 3
// 216.191 us; speedup vs baseline: 1.1512x; 1.1512x over previous
//
#include <hip/hip_runtime.h>
#include <hip/hip_bf16.h>
#include <math.h>

#define GN 12288
#define GE 196608
#define GK 1433
#define GC 32

typedef __attribute__((ext_vector_type(8))) short bf16x8;
typedef __attribute__((ext_vector_type(4))) float f32x4;

static __device__ inline unsigned short f2bf(float f) {
    unsigned u = __float_as_uint(f);
    unsigned r = (u + 0x7fffu + ((u >> 16) & 1u)) >> 16;
    return (unsigned short)r;
}
static __device__ inline float bf2f(unsigned short h) {
    return __uint_as_float(((unsigned)h) << 16);
}

// ---------------- zero ----------------
__global__ void zero_kernel(unsigned* __restrict__ p, int n) {
    int i = blockIdx.x * blockDim.x + threadIdx.x;
    if (i < n) p[i] = 0u;
}

// ---------------- edge degree/count ----------------
__global__ void count_kernel(const int* __restrict__ ei,
                             unsigned* __restrict__ deg,
                             unsigned* __restrict__ cnt) {
    int e = blockIdx.x * blockDim.x + threadIdx.x;
    if (e < GE) {
        atomicAdd(&cnt[ei[e]], 1u);        // src
        atomicAdd(&deg[ei[GE + e]], 1u);   // dst
    }
}

// ---------------- prefix sum: 1024 threads x 12, wave shuffle scan ----------------
__global__ __launch_bounds__(1024) void prefix_kernel(const unsigned* __restrict__ cnt,
                                                      unsigned* __restrict__ offs) {
    __shared__ unsigned wsum[16];
    int t = threadIdx.x;
    int lane = t & 63, w = t >> 6;
    unsigned loc[12];
    unsigned s = 0;
    #pragma unroll
    for (int j = 0; j < 12; ++j) { loc[j] = cnt[t * 12 + j]; s += loc[j]; }
    unsigned v = s;
    #pragma unroll
    for (int d = 1; d < 64; d <<= 1) {
        unsigned u = __shfl_up(v, d, 64);
        if (lane >= d) v += u;
    }
    if (lane == 63) wsum[w] = v;
    __syncthreads();
    if (t < 16) {
        unsigned ws_ = wsum[t];
        #pragma unroll
        for (int d = 1; d < 16; d <<= 1) {
            unsigned u = __shfl_up(ws_, d, 64);
            if (t >= d) ws_ += u;
        }
        wsum[t] = ws_;
    }
    __syncthreads();
    unsigned run = (w > 0 ? wsum[w - 1] : 0u) + (v - s);
    #pragma unroll
    for (int j = 0; j < 12; ++j) { offs[t * 12 + j] = run; run += loc[j]; }
}

// ---------------- scatter into CSR ----------------
__global__ void scatter_kernel(const int* __restrict__ ei,
                               const unsigned* __restrict__ offs,
                               unsigned* __restrict__ cursor,
                               unsigned* __restrict__ adj) {
    int e = blockIdx.x * blockDim.x + threadIdx.x;
    if (e < GE) {
        int src = ei[e];
        unsigned pos = atomicAdd(&cursor[src], 1u);
        adj[offs[src] + pos] = (unsigned)ei[GE + e];
    }
}

// ---------------- GEMM: MFMA bf16 hi/lo split, 128x32 tile, K-split ----------------
// x read once in fp32, converted in-register to (hi,lo) bf16 pairs.
// xw = xh@wh + xh@wl + xl@wh  (ll term ~2^-18, dropped)
__global__ __launch_bounds__(256) void gemm_kernel(const float* __restrict__ x,
                                                   const float* __restrict__ W1,
                                                   float* __restrict__ partial,
                                                   int kchunk) {
    // stride 40 bf16 (=80B): 16B-aligned b128 frags, row offsets spread all 32 banks
    __shared__ unsigned short Ah[128 * 40], Al[128 * 40];
    __shared__ unsigned short Bh[32 * 40], Bl[32 * 40];
    int t = threadIdx.x;
    int lane = t & 63, w = t >> 6;
    int quad = lane >> 4, l15 = lane & 15;
    int row0 = blockIdx.x * 128;
    int ks = blockIdx.y;
    int k0 = ks * kchunk;
    int kend = min(GK, k0 + kchunk);
    f32x4 acc[2][2] = {};

    for (int kb = k0; kb < k0 + kchunk; kb += 32) {
        __syncthreads();
        // ---- stage A: 128 rows x 32 k, coalesced dword loads (rows only 4B-aligned) ----
        {
            int kk = (t & 15) * 2;
            int rbase = t >> 4;
            #pragma unroll
            for (int p = 0; p < 8; ++p) {
                int r = rbase + p * 16;
                const float* xr = x + (size_t)(row0 + r) * GK;
                int k = kb + kk;
                float f0 = (k < kend) ? xr[k] : 0.f;
                float f1 = (k + 1 < kend) ? xr[k + 1] : 0.f;
                unsigned short h0 = f2bf(f0), h1 = f2bf(f1);
                unsigned short l0 = f2bf(f0 - bf2f(h0)), l1 = f2bf(f1 - bf2f(h1));
                *(unsigned*)&Ah[r * 40 + kk] = (unsigned)h0 | ((unsigned)h1 << 16);
                *(unsigned*)&Al[r * 40 + kk] = (unsigned)l0 | ((unsigned)l1 << 16);
            }
        }
        // ---- stage B: W1[kb..kb+31][0..31] transposed -> Bt[c][k] ----
        {
            int c = (t & 15) * 2;
            #pragma unroll
            for (int p = 0; p < 2; ++p) {
                int k = (t >> 4) + p * 16;
                int kg = kb + k;
                const float* wr = W1 + (size_t)kg * GC;
                float f0 = (kg < kend) ? wr[c] : 0.f;
                float f1 = (kg < kend) ? wr[c + 1] : 0.f;
                unsigned short h0 = f2bf(f0), h1 = f2bf(f1);
                unsigned short l0 = f2bf(f0 - bf2f(h0)), l1 = f2bf(f1 - bf2f(h1));
                Bh[c * 40 + k] = h0; Bh[(c + 1) * 40 + k] = h1;
                Bl[c * 40 + k] = l0; Bl[(c + 1) * 40 + k] = l1;
            }
        }
        __syncthreads();
        // ---- fragments + MFMA ----
        bf16x8 ah[2], al[2], bh[2], bl[2];
        #pragma unroll
        for (int mt = 0; mt < 2; ++mt) {
            int r = w * 32 + mt * 16 + l15;
            ah[mt] = *(bf16x8*)&Ah[r * 40 + quad * 8];
            al[mt] = *(bf16x8*)&Al[r * 40 + quad * 8];
        }
        #pragma unroll
        for (int nt = 0; nt < 2; ++nt) {
            int c = nt * 16 + l15;
            bh[nt] = *(bf16x8*)&Bh[c * 40 + quad * 8];
            bl[nt] = *(bf16x8*)&Bl[c * 40 + quad * 8];
        }
        #pragma unroll
        for (int mt = 0; mt < 2; ++mt)
            #pragma unroll
            for (int nt = 0; nt < 2; ++nt) {
                acc[mt][nt] = __builtin_amdgcn_mfma_f32_16x16x32_bf16(ah[mt], bh[nt], acc[mt][nt], 0, 0, 0);
                acc[mt][nt] = __builtin_amdgcn_mfma_f32_16x16x32_bf16(ah[mt], bl[nt], acc[mt][nt], 0, 0, 0);
                acc[mt][nt] = __builtin_amdgcn_mfma_f32_16x16x32_bf16(al[mt], bh[nt], acc[mt][nt], 0, 0, 0);
            }
    }
    // ---- epilogue: C/D layout col=lane&15, row=quad*4+reg ----
    #pragma unroll
    for (int mt = 0; mt < 2; ++mt)
        #pragma unroll
        for (int i = 0; i < 4; ++i) {
            int row = row0 + w * 32 + mt * 16 + quad * 4 + i;
            float* po = partial + ((size_t)ks * GN + row) * GC;
            po[l15] = acc[mt][0][i];
            po[16 + l15] = acc[mt][1][i];
        }
}

// ---------------- reduce K-splits + precompute dis ----------------
__global__ void reduce_kernel(const float* __restrict__ partial, float* __restrict__ xw,
                              const unsigned* __restrict__ deg, float* __restrict__ dis,
                              int nsplit) {
    int i = blockIdx.x * blockDim.x + threadIdx.x;
    const size_t S = (size_t)GN * GC;
    float s = 0.f;
    for (int p = 0; p < nsplit; ++p) s += partial[p * S + i];
    xw[i] = s;
    if (i < GN) dis[i] = rsqrtf((float)(deg[i] + 1u));
}

// ---------------- GCN gather ----------------
__global__ __launch_bounds__(256) void gcn_kernel(const float* __restrict__ xw,
                                                  const float* __restrict__ dis,
                                                  const unsigned* __restrict__ cnt,
                                                  const unsigned* __restrict__ offs,
                                                  const unsigned* __restrict__ adj,
                                                  const float* __restrict__ b1,
                                                  float* __restrict__ h) {
    int w = threadIdx.x >> 6;
    int lane = threadIdx.x & 63;
    int i = blockIdx.x * 4 + w;
    int f = lane & 31, half = lane >> 5;
    unsigned ci = cnt[i], oi = offs[i];
    float acc = 0.f;
    for (unsigned j = half; j < ci; j += 2) {
        unsigned dst = adj[oi + j];
        acc += xw[(size_t)dst * GC + f] * dis[dst];
    }
    acc += __shfl_xor(acc, 32, 64);
    float disi = dis[i];
    float v = b1[f] + disi * (disi * xw[(size_t)i * GC + f] + acc);
    if (half == 0) h[(size_t)i * GC + f] = fmaxf(v, 0.f);
}

// ---------------- SAGE gather + fused head ----------------
__global__ __launch_bounds__(256) void sage_kernel(const float* __restrict__ h,
                                                   const unsigned* __restrict__ cnt,
                                                   const unsigned* __restrict__ offs,
                                                   const unsigned* __restrict__ adj,
                                                   const float* __restrict__ Wl,
                                                   const float* __restrict__ bl,
                                                   const float* __restrict__ Wr,
                                                   const float* __restrict__ br,
                                                   const float* __restrict__ W3,
                                                   const float* __restrict__ b3,
                                                   float* __restrict__ out) {
    __shared__ float sh[4][64];
    __shared__ float so[4][16];
    int w = threadIdx.x >> 6, lane = threadIdx.x & 63;
    int i = blockIdx.x * 4 + w;
    int f = lane & 31, half = lane >> 5;
    unsigned ci = cnt[i], oi = offs[i];
    float acc = 0.f;
    for (unsigned j = half; j < ci; j += 2) acc += h[(size_t)adj[oi + j] * GC + f];
    acc += __shfl_xor(acc, 32, 64);
    float agg = ci ? acc / (float)ci : 0.f;
    float hv = h[(size_t)i * GC + f];
    if (half == 0) { sh[w][f] = hv; sh[w][32 + f] = agg; }
    __syncthreads();
    int c = lane;
    float hid = 0.f;
    if (c < 16) {
        hid = bl[c] + br[c];
        #pragma unroll
        for (int ff = 0; ff < 32; ++ff)
            hid += sh[w][ff] * Wl[ff * 16 + c] + sh[w][32 + ff] * Wr[ff * 16 + c];
        hid = fmaxf(hid, 0.f);
    }
    float n2 = hid * hid;
    n2 += __shfl_xor(n2, 1, 64);
    n2 += __shfl_xor(n2, 2, 64);
    n2 += __shfl_xor(n2, 4, 64);
    n2 += __shfl_xor(n2, 8, 64);
    float o = hid / (sqrtf(n2) + 1e-6f);
    if (c < 16) so[w][c] = o;
    __syncthreads();
    float logit = -INFINITY;
    if (lane < 7) {
        logit = b3[lane];
        #pragma unroll
        for (int cc = 0; cc < 16; ++cc) logit += so[w][cc] * W3[cc * 7 + lane];
    }
    float m = logit;
    m = fmaxf(m, __shfl_xor(m, 1, 64));
    m = fmaxf(m, __shfl_xor(m, 2, 64));
    m = fmaxf(m, __shfl_xor(m, 4, 64));
    float e = expf(logit - m);
    float s = e;
    s += __shfl_xor(s, 1, 64);
    s += __shfl_xor(s, 2, 64);
    s += __shfl_xor(s, 4, 64);
    if (lane < 7) out[(size_t)i * 7 + lane] = e / s;
}

extern "C" void kernel_launch(void* const* d_in, const int* in_sizes, int n_in,
                              void* d_out, int out_size, void* d_ws, size_t ws_size,
                              hipStream_t stream) {
    const float* x  = (const float*)d_in[0];
    const int*   ei = (const int*)d_in[1];
    const float* W1 = (const float*)d_in[2];
    const float* b1 = (const float*)d_in[3];
    const float* Wl = (const float*)d_in[4];
    const float* bl = (const float*)d_in[5];
    const float* Wr = (const float*)d_in[6];
    const float* br = (const float*)d_in[7];
    const float* W3 = (const float*)d_in[8];
    const float* b3 = (const float*)d_in[9];
    float* out = (float*)d_out;

    // K-split: kchunk must be a multiple of 32. 9*160 = 1440 >= 1433.
    const size_t S = (size_t)GN * GC * 4;                 // 1.57 MB
    const size_t fixed = 2 * S + (size_t)GN * 4 * 5 + (size_t)GE * 4;
    int nsplit = (ws_size >= 9 * S + fixed) ? 9 : 3;
    int kchunk = (nsplit == 9) ? 160 : 480;

    char* ws = (char*)d_ws;
    float*    partial = (float*)(ws);
    float*    xw      = (float*)(ws + (size_t)nsplit * S);
    float*    h       = (float*)((char*)xw + S);
    float*    dis     = (float*)((char*)h + S);
    unsigned* deg     = (unsigned*)((char*)dis + (size_t)GN * 4);
    unsigned* cnt     = deg + GN;
    unsigned* cursor  = cnt + GN;
    unsigned* offs    = cursor + GN;
    unsigned* adj     = offs + GN;

    zero_kernel<<<(3 * GN + 255) / 256, 256, 0, stream>>>(deg, 3 * GN);
    count_kernel<<<GE / 256, 256, 0, stream>>>(ei, deg, cnt);
    prefix_kernel<<<1, 1024, 0, stream>>>(cnt, offs);
    scatter_kernel<<<GE / 256, 256, 0, stream>>>(ei, offs, cursor, adj);
    gemm_kernel<<<dim3(GN / 128, nsplit), 256, 0, stream>>>(x, W1, partial, kchunk);
    reduce_kernel<<<(GN * GC) / 256, 256, 0, stream>>>(partial, xw, deg, dis, nsplit);
    gcn_kernel<<<GN / 4, 256, 0, stream>>>(xw, dis, cnt, offs, adj, b1, h);
    sage_kernel<<<GN / 4, 256, 0, stream>>>(h, cnt, offs, adj, Wl, bl, Wr, br, W3, b3, out);
}

// Round 4
// 209.713 us; speedup vs baseline: 1.1868x; 1.0309x over previous
//
#include <hip/hip_runtime.h>
#include <hip/hip_bf16.h>
#include <math.h>

#define GN 12288
#define GE 196608
#define GK 1433
#define GC 32

typedef __attribute__((ext_vector_type(8))) short bf16x8;
typedef __attribute__((ext_vector_type(4))) float f32x4;

static __device__ inline unsigned short f2bf(float f) {
    unsigned u = __float_as_uint(f);
    unsigned r = (u + 0x7fffu + ((u >> 16) & 1u)) >> 16;
    return (unsigned short)r;
}
static __device__ inline float bf2f(unsigned short h) {
    return __uint_as_float(((unsigned)h) << 16);
}

// ---------------- edge degree/count ----------------
__global__ void count_kernel(const int* __restrict__ ei,
                             unsigned* __restrict__ deg,
                             unsigned* __restrict__ cnt) {
    int e = blockIdx.x * blockDim.x + threadIdx.x;
    if (e < GE) {
        atomicAdd(&cnt[ei[e]], 1u);        // src
        atomicAdd(&deg[ei[GE + e]], 1u);   // dst
    }
}

// ---------------- prefix sum: 1024 threads x 12, wave shuffle scan ----------------
__global__ __launch_bounds__(1024) void prefix_kernel(const unsigned* __restrict__ cnt,
                                                      unsigned* __restrict__ offs) {
    __shared__ unsigned wsum[16];
    int t = threadIdx.x;
    int lane = t & 63, w = t >> 6;
    unsigned loc[12];
    unsigned s = 0;
    #pragma unroll
    for (int j = 0; j < 12; ++j) { loc[j] = cnt[t * 12 + j]; s += loc[j]; }
    unsigned v = s;
    #pragma unroll
    for (int d = 1; d < 64; d <<= 1) {
        unsigned u = __shfl_up(v, d, 64);
        if (lane >= d) v += u;
    }
    if (lane == 63) wsum[w] = v;
    __syncthreads();
    if (t < 16) {
        unsigned ws_ = wsum[t];
        #pragma unroll
        for (int d = 1; d < 16; d <<= 1) {
            unsigned u = __shfl_up(ws_, d, 64);
            if (t >= d) ws_ += u;
        }
        wsum[t] = ws_;
    }
    __syncthreads();
    unsigned run = (w > 0 ? wsum[w - 1] : 0u) + (v - s);
    #pragma unroll
    for (int j = 0; j < 12; ++j) { offs[t * 12 + j] = run; run += loc[j]; }
}

// ---------------- scatter into CSR ----------------
__global__ void scatter_kernel(const int* __restrict__ ei,
                               const unsigned* __restrict__ offs,
                               unsigned* __restrict__ cursor,
                               unsigned* __restrict__ adj) {
    int e = blockIdx.x * blockDim.x + threadIdx.x;
    if (e < GE) {
        int src = ei[e];
        unsigned pos = atomicAdd(&cursor[src], 1u);
        adj[offs[src] + pos] = (unsigned)ei[GE + e];
    }
}

// ---------------- GEMM: MFMA bf16 hi/lo split, register-double-buffered staging ----
struct Pref { float a[16]; float b[4]; };

static __device__ inline void fetch(Pref& p, const float* __restrict__ x,
                                    const float* __restrict__ W1,
                                    int row0, int kb, int kend, int t) {
    int akk = (t & 15) * 2, arb = t >> 4;
    #pragma unroll
    for (int q = 0; q < 8; ++q) {
        int r = arb + q * 16;
        int k = kb + akk;
        const float* xp = x + (size_t)(row0 + r) * GK;
        p.a[2 * q]     = (k < kend) ? xp[k] : 0.f;
        p.a[2 * q + 1] = (k + 1 < kend) ? xp[k + 1] : 0.f;
    }
    int c = (t & 15) * 2;
    #pragma unroll
    for (int q = 0; q < 2; ++q) {
        int kg = kb + (t >> 4) + q * 16;
        const float* wr = W1 + (size_t)kg * GC;
        bool vld = kg < kend;
        p.b[2 * q]     = vld ? wr[c] : 0.f;
        p.b[2 * q + 1] = vld ? wr[c + 1] : 0.f;
    }
}

static __device__ inline void stage(const Pref& p,
                                    unsigned short* __restrict__ Ah, unsigned short* __restrict__ Al,
                                    unsigned short* __restrict__ Bh, unsigned short* __restrict__ Bl,
                                    int t) {
    int akk = (t & 15) * 2, arb = t >> 4;
    #pragma unroll
    for (int q = 0; q < 8; ++q) {
        int r = arb + q * 16;
        float f0 = p.a[2 * q], f1 = p.a[2 * q + 1];
        unsigned short h0 = f2bf(f0), h1 = f2bf(f1);
        unsigned short l0 = f2bf(f0 - bf2f(h0)), l1 = f2bf(f1 - bf2f(h1));
        *(unsigned*)&Ah[r * 40 + akk] = (unsigned)h0 | ((unsigned)h1 << 16);
        *(unsigned*)&Al[r * 40 + akk] = (unsigned)l0 | ((unsigned)l1 << 16);
    }
    int c = (t & 15) * 2;
    #pragma unroll
    for (int q = 0; q < 2; ++q) {
        int k = (t >> 4) + q * 16;
        float f0 = p.b[2 * q], f1 = p.b[2 * q + 1];
        unsigned short h0 = f2bf(f0), h1 = f2bf(f1);
        unsigned short l0 = f2bf(f0 - bf2f(h0)), l1 = f2bf(f1 - bf2f(h1));
        Bh[c * 40 + k] = h0; Bh[(c + 1) * 40 + k] = h1;
        Bl[c * 40 + k] = l0; Bl[(c + 1) * 40 + k] = l1;
    }
}

__global__ __launch_bounds__(256) void gemm_kernel(const float* __restrict__ x,
                                                   const float* __restrict__ W1,
                                                   float* __restrict__ partial,
                                                   int kchunk) {
    __shared__ unsigned short Ah[128 * 40], Al[128 * 40];
    __shared__ unsigned short Bh[32 * 40], Bl[32 * 40];
    int t = threadIdx.x;
    int lane = t & 63, w = t >> 6;
    int quad = lane >> 4, l15 = lane & 15;
    int row0 = blockIdx.x * 128;
    int ks = blockIdx.y;
    int k0 = ks * kchunk;
    int kend = min(GK, k0 + kchunk);
    f32x4 acc[2][2] = {};

    Pref cur, nxt;
    fetch(cur, x, W1, row0, k0, kend, t);

    for (int kb = k0; kb < kend; kb += 32) {
        if (kb + 32 < kend) fetch(nxt, x, W1, row0, kb + 32, kend, t);
        stage(cur, Ah, Al, Bh, Bl, t);
        __syncthreads();
        bf16x8 ah[2], al[2], bh[2], bl[2];
        #pragma unroll
        for (int mt = 0; mt < 2; ++mt) {
            int r = w * 32 + mt * 16 + l15;
            ah[mt] = *(bf16x8*)&Ah[r * 40 + quad * 8];
            al[mt] = *(bf16x8*)&Al[r * 40 + quad * 8];
        }
        #pragma unroll
        for (int nt = 0; nt < 2; ++nt) {
            int c = nt * 16 + l15;
            bh[nt] = *(bf16x8*)&Bh[c * 40 + quad * 8];
            bl[nt] = *(bf16x8*)&Bl[c * 40 + quad * 8];
        }
        #pragma unroll
        for (int mt = 0; mt < 2; ++mt)
            #pragma unroll
            for (int nt = 0; nt < 2; ++nt) {
                acc[mt][nt] = __builtin_amdgcn_mfma_f32_16x16x32_bf16(ah[mt], bh[nt], acc[mt][nt], 0, 0, 0);
                acc[mt][nt] = __builtin_amdgcn_mfma_f32_16x16x32_bf16(ah[mt], bl[nt], acc[mt][nt], 0, 0, 0);
                acc[mt][nt] = __builtin_amdgcn_mfma_f32_16x16x32_bf16(al[mt], bh[nt], acc[mt][nt], 0, 0, 0);
            }
        __syncthreads();
        cur = nxt;
    }
    // ---- epilogue: C/D layout col=lane&15, row=quad*4+reg ----
    #pragma unroll
    for (int mt = 0; mt < 2; ++mt)
        #pragma unroll
        for (int i = 0; i < 4; ++i) {
            int row = row0 + w * 32 + mt * 16 + quad * 4 + i;
            float* po = partial + ((size_t)ks * GN + row) * GC;
            po[l15] = acc[mt][0][i];
            po[16 + l15] = acc[mt][1][i];
        }
}

// ---------------- reduce K-splits + precompute dis ----------------
__global__ void reduce_kernel(const float* __restrict__ partial, float* __restrict__ xw,
                              const unsigned* __restrict__ deg, float* __restrict__ dis,
                              int nsplit) {
    int i = blockIdx.x * blockDim.x + threadIdx.x;
    const size_t S = (size_t)GN * GC;
    float s = 0.f;
    for (int p = 0; p < nsplit; ++p) s += partial[p * S + i];
    xw[i] = s;
    if (i < GN) dis[i] = rsqrtf((float)(deg[i] + 1u));
}

// ---------------- GCN gather ----------------
__global__ __launch_bounds__(256) void gcn_kernel(const float* __restrict__ xw,
                                                  const float* __restrict__ dis,
                                                  const unsigned* __restrict__ cnt,
                                                  const unsigned* __restrict__ offs,
                                                  const unsigned* __restrict__ adj,
                                                  const float* __restrict__ b1,
                                                  float* __restrict__ h) {
    int w = threadIdx.x >> 6;
    int lane = threadIdx.x & 63;
    int i = blockIdx.x * 4 + w;
    int f = lane & 31, half = lane >> 5;
    unsigned ci = cnt[i], oi = offs[i];
    float acc = 0.f;
    for (unsigned j = half; j < ci; j += 2) {
        unsigned dst = adj[oi + j];
        acc += xw[(size_t)dst * GC + f] * dis[dst];
    }
    acc += __shfl_xor(acc, 32, 64);
    float disi = dis[i];
    float v = b1[f] + disi * (disi * xw[(size_t)i * GC + f] + acc);
    if (half == 0) h[(size_t)i * GC + f] = fmaxf(v, 0.f);
}

// ---------------- SAGE gather + fused head ----------------
__global__ __launch_bounds__(256) void sage_kernel(const float* __restrict__ h,
                                                   const unsigned* __restrict__ cnt,
                                                   const unsigned* __restrict__ offs,
                                                   const unsigned* __restrict__ adj,
                                                   const float* __restrict__ Wl,
                                                   const float* __restrict__ bl,
                                                   const float* __restrict__ Wr,
                                                   const float* __restrict__ br,
                                                   const float* __restrict__ W3,
                                                   const float* __restrict__ b3,
                                                   float* __restrict__ out) {
    __shared__ float sh[4][64];
    __shared__ float so[4][16];
    int w = threadIdx.x >> 6, lane = threadIdx.x & 63;
    int i = blockIdx.x * 4 + w;
    int f = lane & 31, half = lane >> 5;
    unsigned ci = cnt[i], oi = offs[i];
    float acc = 0.f;
    for (unsigned j = half; j < ci; j += 2) acc += h[(size_t)adj[oi + j] * GC + f];
    acc += __shfl_xor(acc, 32, 64);
    float agg = ci ? acc / (float)ci : 0.f;
    float hv = h[(size_t)i * GC + f];
    if (half == 0) { sh[w][f] = hv; sh[w][32 + f] = agg; }
    __syncthreads();
    int c = lane;
    float hid = 0.f;
    if (c < 16) {
        hid = bl[c] + br[c];
        #pragma unroll
        for (int ff = 0; ff < 32; ++ff)
            hid += sh[w][ff] * Wl[ff * 16 + c] + sh[w][32 + ff] * Wr[ff * 16 + c];
        hid = fmaxf(hid, 0.f);
    }
    float n2 = hid * hid;
    n2 += __shfl_xor(n2, 1, 64);
    n2 += __shfl_xor(n2, 2, 64);
    n2 += __shfl_xor(n2, 4, 64);
    n2 += __shfl_xor(n2, 8, 64);
    float o = hid / (sqrtf(n2) + 1e-6f);
    if (c < 16) so[w][c] = o;
    __syncthreads();
    float logit = -INFINITY;
    if (lane < 7) {
        logit = b3[lane];
        #pragma unroll
        for (int cc = 0; cc < 16; ++cc) logit += so[w][cc] * W3[cc * 7 + lane];
    }
    float m = logit;
    m = fmaxf(m, __shfl_xor(m, 1, 64));
    m = fmaxf(m, __shfl_xor(m, 2, 64));
    m = fmaxf(m, __shfl_xor(m, 4, 64));
    float e = expf(logit - m);
    float s = e;
    s += __shfl_xor(s, 1, 64);
    s += __shfl_xor(s, 2, 64);
    s += __shfl_xor(s, 4, 64);
    if (lane < 7) out[(size_t)i * 7 + lane] = e / s;
}

extern "C" void kernel_launch(void* const* d_in, const int* in_sizes, int n_in,
                              void* d_out, int out_size, void* d_ws, size_t ws_size,
                              hipStream_t stream) {
    const float* x  = (const float*)d_in[0];
    const int*   ei = (const int*)d_in[1];
    const float* W1 = (const float*)d_in[2];
    const float* b1 = (const float*)d_in[3];
    const float* Wl = (const float*)d_in[4];
    const float* bl = (const float*)d_in[5];
    const float* Wr = (const float*)d_in[6];
    const float* br = (const float*)d_in[7];
    const float* W3 = (const float*)d_in[8];
    const float* b3 = (const float*)d_in[9];
    float* out = (float*)d_out;

    // K-split: kchunk multiple of 32.
    const size_t S = (size_t)GN * GC * 4;                 // 1.57 MB
    const size_t fixed = 2 * S + (size_t)GN * 4 * 5 + (size_t)GE * 4;
    int nsplit, kchunk;
    if (ws_size >= 12 * S + fixed)      { nsplit = 12; kchunk = 128; }
    else if (ws_size >= 9 * S + fixed)  { nsplit = 9;  kchunk = 160; }
    else                                { nsplit = 3;  kchunk = 480; }

    char* ws = (char*)d_ws;
    float*    partial = (float*)(ws);
    float*    xw      = (float*)(ws + (size_t)nsplit * S);
    float*    h       = (float*)((char*)xw + S);
    float*    dis     = (float*)((char*)h + S);
    unsigned* deg     = (unsigned*)((char*)dis + (size_t)GN * 4);
    unsigned* cnt     = deg + GN;
    unsigned* cursor  = cnt + GN;
    unsigned* offs    = cursor + GN;
    unsigned* adj     = offs + GN;

    hipMemsetAsync(deg, 0, 3 * GN * sizeof(unsigned), stream);
    count_kernel<<<GE / 256, 256, 0, stream>>>(ei, deg, cnt);
    prefix_kernel<<<1, 1024, 0, stream>>>(cnt, offs);
    scatter_kernel<<<GE / 256, 256, 0, stream>>>(ei, offs, cursor, adj);
    gemm_kernel<<<dim3(GN / 128, nsplit), 256, 0, stream>>>(x, W1, partial, kchunk);
    reduce_kernel<<<(GN * GC) / 256, 256, 0, stream>>>(partial, xw, deg, dis, nsplit);
    gcn_kernel<<<GN / 4, 256, 0, stream>>>(xw, dis, cnt, offs, adj, b1, h);
    sage_kernel<<<GN / 4, 256, 0, stream>>>(h, cnt, offs, adj, Wl, bl, Wr, br, W3, b3, out);
}

// Round 5
// 208.759 us; speedup vs baseline: 1.1922x; 1.0046x over previous
//
#include <hip/hip_runtime.h>
#include <hip/hip_bf16.h>
#include <math.h>

#define GN 12288
#define GE 196608
#define GK 1433
#define GC 32
#define BSTR 136  // bf16 stride for B tiles: 16B-aligned b128 frags

typedef __attribute__((ext_vector_type(8))) short bf16x8;
typedef __attribute__((ext_vector_type(4))) float f32x4;

static __device__ inline unsigned short f2bf(float f) {
    unsigned u = __float_as_uint(f);
    unsigned r = (u + 0x7fffu + ((u >> 16) & 1u)) >> 16;
    return (unsigned short)r;
}
static __device__ inline float bf2f(unsigned short h) {
    return __uint_as_float(((unsigned)h) << 16);
}

// ---------------- edge degree/count ----------------
__global__ void count_kernel(const int* __restrict__ ei,
                             unsigned* __restrict__ deg,
                             unsigned* __restrict__ cnt) {
    int e = blockIdx.x * blockDim.x + threadIdx.x;
    if (e < GE) {
        atomicAdd(&cnt[ei[e]], 1u);        // src
        atomicAdd(&deg[ei[GE + e]], 1u);   // dst
    }
}

// ---------------- prefix sum: 1024 threads x 12, wave shuffle scan ----------------
__global__ __launch_bounds__(1024) void prefix_kernel(const unsigned* __restrict__ cnt,
                                                      unsigned* __restrict__ offs) {
    __shared__ unsigned wsum[16];
    int t = threadIdx.x;
    int lane = t & 63, w = t >> 6;
    unsigned loc[12];
    unsigned s = 0;
    #pragma unroll
    for (int j = 0; j < 12; ++j) { loc[j] = cnt[t * 12 + j]; s += loc[j]; }
    unsigned v = s;
    #pragma unroll
    for (int d = 1; d < 64; d <<= 1) {
        unsigned u = __shfl_up(v, d, 64);
        if (lane >= d) v += u;
    }
    if (lane == 63) wsum[w] = v;
    __syncthreads();
    if (t < 16) {
        unsigned ws_ = wsum[t];
        #pragma unroll
        for (int d = 1; d < 16; d <<= 1) {
            unsigned u = __shfl_up(ws_, d, 64);
            if (t >= d) ws_ += u;
        }
        wsum[t] = ws_;
    }
    __syncthreads();
    unsigned run = (w > 0 ? wsum[w - 1] : 0u) + (v - s);
    #pragma unroll
    for (int j = 0; j < 12; ++j) { offs[t * 12 + j] = run; run += loc[j]; }
}

// ---------------- scatter into CSR ----------------
__global__ void scatter_kernel(const int* __restrict__ ei,
                               const unsigned* __restrict__ offs,
                               unsigned* __restrict__ cursor,
                               unsigned* __restrict__ adj) {
    int e = blockIdx.x * blockDim.x + threadIdx.x;
    if (e < GE) {
        int src = ei[e];
        unsigned pos = atomicAdd(&cursor[src], 1u);
        adj[offs[src] + pos] = (unsigned)ei[GE + e];
    }
}

// ---------------- GEMM: A direct global->reg, B in LDS, barrier-free inner loop ----
// xw = xh@wh + xh@wl + xl@wh  (ll term ~2^-18, dropped)
__global__ __launch_bounds__(256) void gemm_kernel(const float* __restrict__ x,
                                                   const float* __restrict__ W1,
                                                   float* __restrict__ partial,
                                                   int kchunk) {
    __shared__ unsigned short Bh[32 * BSTR], Bl[32 * BSTR];
    int t = threadIdx.x;
    int lane = t & 63, w = t >> 6;
    int quad = lane >> 4, l15 = lane & 15;
    int row0 = blockIdx.x * 128;
    int ks = blockIdx.y;
    int k0 = ks * kchunk;
    int kend = min(GK, k0 + kchunk);
    f32x4 acc[2][2] = {};

    const float* xr0 = x + (size_t)(row0 + w * 32 + l15) * GK;       // mt=0 row
    const float* xr1 = xr0 + 16 * GK;                                 // mt=1 row

    for (int ksb = k0; ksb < kend; ksb += 128) {
        __syncthreads();
        // ---- stage B superblock: W1[ksb..ksb+128) x 32 cols, hi/lo bf16, zero past kend
        #pragma unroll
        for (int e = 0; e < 16; ++e) {
            int idx = e * 256 + t;
            int kk = idx >> 5, c = idx & 31;
            int kg = ksb + kk;
            float f = (kg < kend) ? W1[(size_t)kg * GC + c] : 0.f;
            unsigned short h = f2bf(f);
            unsigned short l = f2bf(f - bf2f(h));
            Bh[c * BSTR + kk] = h;
            Bl[c * BSTR + kk] = l;
        }
        __syncthreads();
        int kbe = min(128, kend - ksb);
        // ---- barrier-free MFMA loop over 32-k blocks
        #pragma unroll 2
        for (int kb2 = 0; kb2 < kbe; kb2 += 32) {
            int kq = ksb + kb2 + quad * 8;
            float af0[8], af1[8];
            if (kq + 8 <= GK) {
                #pragma unroll
                for (int j = 0; j < 8; ++j) { af0[j] = xr0[kq + j]; af1[j] = xr1[kq + j]; }
            } else {
                #pragma unroll
                for (int j = 0; j < 8; ++j) {
                    bool v = (kq + j) < GK;
                    af0[j] = v ? xr0[kq + j] : 0.f;
                    af1[j] = v ? xr1[kq + j] : 0.f;
                }
            }
            bf16x8 ah[2], al[2];
            #pragma unroll
            for (int j = 0; j < 8; ++j) {
                unsigned short h0 = f2bf(af0[j]);
                ah[0][j] = (short)h0; al[0][j] = (short)f2bf(af0[j] - bf2f(h0));
                unsigned short h1 = f2bf(af1[j]);
                ah[1][j] = (short)h1; al[1][j] = (short)f2bf(af1[j] - bf2f(h1));
            }
            bf16x8 bh[2], bl[2];
            #pragma unroll
            for (int nt = 0; nt < 2; ++nt) {
                int c = nt * 16 + l15;
                bh[nt] = *(bf16x8*)&Bh[c * BSTR + kb2 + quad * 8];
                bl[nt] = *(bf16x8*)&Bl[c * BSTR + kb2 + quad * 8];
            }
            #pragma unroll
            for (int mt = 0; mt < 2; ++mt)
                #pragma unroll
                for (int nt = 0; nt < 2; ++nt) {
                    acc[mt][nt] = __builtin_amdgcn_mfma_f32_16x16x32_bf16(ah[mt], bh[nt], acc[mt][nt], 0, 0, 0);
                    acc[mt][nt] = __builtin_amdgcn_mfma_f32_16x16x32_bf16(ah[mt], bl[nt], acc[mt][nt], 0, 0, 0);
                    acc[mt][nt] = __builtin_amdgcn_mfma_f32_16x16x32_bf16(al[mt], bh[nt], acc[mt][nt], 0, 0, 0);
                }
        }
    }
    // ---- epilogue: C/D layout col=lane&15, row=quad*4+reg ----
    #pragma unroll
    for (int mt = 0; mt < 2; ++mt)
        #pragma unroll
        for (int i = 0; i < 4; ++i) {
            int row = row0 + w * 32 + mt * 16 + quad * 4 + i;
            float* po = partial + ((size_t)ks * GN + row) * GC;
            po[l15] = acc[mt][0][i];
            po[16 + l15] = acc[mt][1][i];
        }
}

// ---------------- reduce K-splits + precompute dis ----------------
__global__ void reduce_kernel(const float* __restrict__ partial, float* __restrict__ xw,
                              const unsigned* __restrict__ deg, float* __restrict__ dis,
                              int nsplit) {
    int i = blockIdx.x * blockDim.x + threadIdx.x;
    const size_t S = (size_t)GN * GC;
    float s = 0.f;
    for (int p = 0; p < nsplit; ++p) s += partial[p * S + i];
    xw[i] = s;
    if (i < GN) dis[i] = rsqrtf((float)(deg[i] + 1u));
}

// ---------------- GCN gather ----------------
__global__ __launch_bounds__(256) void gcn_kernel(const float* __restrict__ xw,
                                                  const float* __restrict__ dis,
                                                  const unsigned* __restrict__ cnt,
                                                  const unsigned* __restrict__ offs,
                                                  const unsigned* __restrict__ adj,
                                                  const float* __restrict__ b1,
                                                  float* __restrict__ h) {
    int w = threadIdx.x >> 6;
    int lane = threadIdx.x & 63;
    int i = blockIdx.x * 4 + w;
    int f = lane & 31, half = lane >> 5;
    unsigned ci = cnt[i], oi = offs[i];
    float acc = 0.f;
    for (unsigned j = half; j < ci; j += 2) {
        unsigned dst = adj[oi + j];
        acc += xw[(size_t)dst * GC + f] * dis[dst];
    }
    acc += __shfl_xor(acc, 32, 64);
    float disi = dis[i];
    float v = b1[f] + disi * (disi * xw[(size_t)i * GC + f] + acc);
    if (half == 0) h[(size_t)i * GC + f] = fmaxf(v, 0.f);
}

// ---------------- SAGE gather + fused head ----------------
__global__ __launch_bounds__(256) void sage_kernel(const float* __restrict__ h,
                                                   const unsigned* __restrict__ cnt,
                                                   const unsigned* __restrict__ offs,
                                                   const unsigned* __restrict__ adj,
                                                   const float* __restrict__ Wl,
                                                   const float* __restrict__ bl,
                                                   const float* __restrict__ Wr,
                                                   const float* __restrict__ br,
                                                   const float* __restrict__ W3,
                                                   const float* __restrict__ b3,
                                                   float* __restrict__ out) {
    __shared__ float sh[4][64];
    __shared__ float so[4][16];
    int w = threadIdx.x >> 6, lane = threadIdx.x & 63;
    int i = blockIdx.x * 4 + w;
    int f = lane & 31, half = lane >> 5;
    unsigned ci = cnt[i], oi = offs[i];
    float acc = 0.f;
    for (unsigned j = half; j < ci; j += 2) acc += h[(size_t)adj[oi + j] * GC + f];
    acc += __shfl_xor(acc, 32, 64);
    float agg = ci ? acc / (float)ci : 0.f;
    float hv = h[(size_t)i * GC + f];
    if (half == 0) { sh[w][f] = hv; sh[w][32 + f] = agg; }
    __syncthreads();
    int c = lane;
    float hid = 0.f;
    if (c < 16) {
        hid = bl[c] + br[c];
        #pragma unroll
        for (int ff = 0; ff < 32; ++ff)
            hid += sh[w][ff] * Wl[ff * 16 + c] + sh[w][32 + ff] * Wr[ff * 16 + c];
        hid = fmaxf(hid, 0.f);
    }
    float n2 = hid * hid;
    n2 += __shfl_xor(n2, 1, 64);
    n2 += __shfl_xor(n2, 2, 64);
    n2 += __shfl_xor(n2, 4, 64);
    n2 += __shfl_xor(n2, 8, 64);
    float o = hid / (sqrtf(n2) + 1e-6f);
    if (c < 16) so[w][c] = o;
    __syncthreads();
    float logit = -INFINITY;
    if (lane < 7) {
        logit = b3[lane];
        #pragma unroll
        for (int cc = 0; cc < 16; ++cc) logit += so[w][cc] * W3[cc * 7 + lane];
    }
    float m = logit;
    m = fmaxf(m, __shfl_xor(m, 1, 64));
    m = fmaxf(m, __shfl_xor(m, 2, 64));
    m = fmaxf(m, __shfl_xor(m, 4, 64));
    float e = expf(logit - m);
    float s = e;
    s += __shfl_xor(s, 1, 64);
    s += __shfl_xor(s, 2, 64);
    s += __shfl_xor(s, 4, 64);
    if (lane < 7) out[(size_t)i * 7 + lane] = e / s;
}

extern "C" void kernel_launch(void* const* d_in, const int* in_sizes, int n_in,
                              void* d_out, int out_size, void* d_ws, size_t ws_size,
                              hipStream_t stream) {
    const float* x  = (const float*)d_in[0];
    const int*   ei = (const int*)d_in[1];
    const float* W1 = (const float*)d_in[2];
    const float* b1 = (const float*)d_in[3];
    const float* Wl = (const float*)d_in[4];
    const float* bl = (const float*)d_in[5];
    const float* Wr = (const float*)d_in[6];
    const float* br = (const float*)d_in[7];
    const float* W3 = (const float*)d_in[8];
    const float* b3 = (const float*)d_in[9];
    float* out = (float*)d_out;

    // K-split: kchunk multiple of 32.
    const size_t S = (size_t)GN * GC * 4;                 // 1.57 MB
    const size_t fixed = 2 * S + (size_t)GN * 4 * 5 + (size_t)GE * 4;
    int nsplit, kchunk;
    if (ws_size >= 12 * S + fixed)      { nsplit = 12; kchunk = 128; }
    else if (ws_size >= 9 * S + fixed)  { nsplit = 9;  kchunk = 160; }
    else                                { nsplit = 3;  kchunk = 480; }

    char* ws = (char*)d_ws;
    float*    partial = (float*)(ws);
    float*    xw      = (float*)(ws + (size_t)nsplit * S);
    float*    h       = (float*)((char*)xw + S);
    float*    dis     = (float*)((char*)h + S);
    unsigned* deg     = (unsigned*)((char*)dis + (size_t)GN * 4);
    unsigned* cnt     = deg + GN;
    unsigned* cursor  = cnt + GN;
    unsigned* offs    = cursor + GN;
    unsigned* adj     = offs + GN;

    hipMemsetAsync(deg, 0, 3 * GN * sizeof(unsigned), stream);
    count_kernel<<<GE / 256, 256, 0, stream>>>(ei, deg, cnt);
    prefix_kernel<<<1, 1024, 0, stream>>>(cnt, offs);
    scatter_kernel<<<GE / 256, 256, 0, stream>>>(ei, offs, cursor, adj);
    gemm_kernel<<<dim3(GN / 128, nsplit), 256, 0, stream>>>(x, W1, partial, kchunk);
    reduce_kernel<<<(GN * GC) / 256, 256, 0, stream>>>(partial, xw, deg, dis, nsplit);
    gcn_kernel<<<GN / 4, 256, 0, stream>>>(xw, dis, cnt, offs, adj, b1, h);
    sage_kernel<<<GN / 4, 256, 0, stream>>>(h, cnt, offs, adj, Wl, bl, Wr, br, W3, b3, out);
}

// Round 6
// 196.525 us; speedup vs baseline: 1.2664x; 1.0622x over previous
//
#include <hip/hip_runtime.h>
#include <hip/hip_bf16.h>
#include <math.h>

#define GN 12288
#define GE 196608
#define GK 1433
#define GC 32
#define BSTR 136  // bf16 stride for B tiles: 16B-aligned b128 frags

typedef __attribute__((ext_vector_type(8))) short bf16x8;
typedef __attribute__((ext_vector_type(4))) float f32x4;

static __device__ inline unsigned short f2bf(float f) {
    unsigned u = __float_as_uint(f);
    unsigned r = (u + 0x7fffu + ((u >> 16) & 1u)) >> 16;
    return (unsigned short)r;
}
static __device__ inline float bf2f(unsigned short h) {
    return __uint_as_float(((unsigned)h) << 16);
}

// ---------------- edge degree/count + zero xw for atomic epilogue ----------------
__global__ void count_kernel(const int* __restrict__ ei,
                             unsigned* __restrict__ deg,
                             unsigned* __restrict__ cnt,
                             float* __restrict__ xw) {
    int e = blockIdx.x * blockDim.x + threadIdx.x;
    // zero xw (GN*GC = 2*GE elements)
    xw[e] = 0.f;
    xw[e + GE] = 0.f;
    atomicAdd(&cnt[ei[e]], 1u);        // src
    atomicAdd(&deg[ei[GE + e]], 1u);   // dst
}

// ---------------- prefix sum + dis: 1024 threads x 12, wave shuffle scan --------
__global__ __launch_bounds__(1024) void prefix_kernel(const unsigned* __restrict__ cnt,
                                                      unsigned* __restrict__ offs,
                                                      const unsigned* __restrict__ deg,
                                                      float* __restrict__ dis) {
    __shared__ unsigned wsum[16];
    int t = threadIdx.x;
    int lane = t & 63, w = t >> 6;
    unsigned loc[12];
    unsigned s = 0;
    #pragma unroll
    for (int j = 0; j < 12; ++j) { loc[j] = cnt[t * 12 + j]; s += loc[j]; }
    unsigned v = s;
    #pragma unroll
    for (int d = 1; d < 64; d <<= 1) {
        unsigned u = __shfl_up(v, d, 64);
        if (lane >= d) v += u;
    }
    if (lane == 63) wsum[w] = v;
    __syncthreads();
    if (t < 16) {
        unsigned ws_ = wsum[t];
        #pragma unroll
        for (int d = 1; d < 16; d <<= 1) {
            unsigned u = __shfl_up(ws_, d, 64);
            if (t >= d) ws_ += u;
        }
        wsum[t] = ws_;
    }
    __syncthreads();
    unsigned run = (w > 0 ? wsum[w - 1] : 0u) + (v - s);
    #pragma unroll
    for (int j = 0; j < 12; ++j) { offs[t * 12 + j] = run; run += loc[j]; }
    #pragma unroll
    for (int j = 0; j < 12; ++j) {
        int i = t * 12 + j;
        dis[i] = rsqrtf((float)(deg[i] + 1u));
    }
}

// ---------------- scatter into CSR ----------------
__global__ void scatter_kernel(const int* __restrict__ ei,
                               const unsigned* __restrict__ offs,
                               unsigned* __restrict__ cursor,
                               unsigned* __restrict__ adj) {
    int e = blockIdx.x * blockDim.x + threadIdx.x;
    if (e < GE) {
        int src = ei[e];
        unsigned pos = atomicAdd(&cursor[src], 1u);
        adj[offs[src] + pos] = (unsigned)ei[GE + e];
    }
}

// ---------------- GEMM: A direct global->reg, B in LDS, atomic-add epilogue ----
// xw += xh@wh + xh@wl + xl@wh  (ll term ~2^-18, dropped)
__global__ __launch_bounds__(256) void gemm_kernel(const float* __restrict__ x,
                                                   const float* __restrict__ W1,
                                                   float* __restrict__ xw,
                                                   int kchunk) {
    __shared__ unsigned short Bh[32 * BSTR], Bl[32 * BSTR];
    int t = threadIdx.x;
    int lane = t & 63, w = t >> 6;
    int quad = lane >> 4, l15 = lane & 15;
    int row0 = blockIdx.x * 128;
    int ks = blockIdx.y;
    int k0 = ks * kchunk;
    int kend = min(GK, k0 + kchunk);
    f32x4 acc[2][2] = {};

    const float* xr0 = x + (size_t)(row0 + w * 32 + l15) * GK;       // mt=0 row
    const float* xr1 = xr0 + 16 * GK;                                 // mt=1 row

    for (int ksb = k0; ksb < kend; ksb += 128) {
        __syncthreads();
        // ---- stage B superblock: W1[ksb..ksb+128) x 32 cols, hi/lo bf16, zero past kend
        #pragma unroll
        for (int e = 0; e < 16; ++e) {
            int idx = e * 256 + t;
            int kk = idx >> 5, c = idx & 31;
            int kg = ksb + kk;
            float f = (kg < kend) ? W1[(size_t)kg * GC + c] : 0.f;
            unsigned short h = f2bf(f);
            unsigned short l = f2bf(f - bf2f(h));
            Bh[c * BSTR + kk] = h;
            Bl[c * BSTR + kk] = l;
        }
        __syncthreads();
        int kbe = min(128, kend - ksb);
        // ---- barrier-free MFMA loop over 32-k blocks
        #pragma unroll 2
        for (int kb2 = 0; kb2 < kbe; kb2 += 32) {
            int kq = ksb + kb2 + quad * 8;
            float af0[8], af1[8];
            if (kq + 8 <= GK) {
                #pragma unroll
                for (int j = 0; j < 8; ++j) { af0[j] = xr0[kq + j]; af1[j] = xr1[kq + j]; }
            } else {
                #pragma unroll
                for (int j = 0; j < 8; ++j) {
                    bool v = (kq + j) < GK;
                    af0[j] = v ? xr0[kq + j] : 0.f;
                    af1[j] = v ? xr1[kq + j] : 0.f;
                }
            }
            bf16x8 ah[2], al[2];
            #pragma unroll
            for (int j = 0; j < 8; ++j) {
                unsigned short h0 = f2bf(af0[j]);
                ah[0][j] = (short)h0; al[0][j] = (short)f2bf(af0[j] - bf2f(h0));
                unsigned short h1 = f2bf(af1[j]);
                ah[1][j] = (short)h1; al[1][j] = (short)f2bf(af1[j] - bf2f(h1));
            }
            bf16x8 bh[2], bl[2];
            #pragma unroll
            for (int nt = 0; nt < 2; ++nt) {
                int c = nt * 16 + l15;
                bh[nt] = *(bf16x8*)&Bh[c * BSTR + kb2 + quad * 8];
                bl[nt] = *(bf16x8*)&Bl[c * BSTR + kb2 + quad * 8];
            }
            #pragma unroll
            for (int mt = 0; mt < 2; ++mt)
                #pragma unroll
                for (int nt = 0; nt < 2; ++nt) {
                    acc[mt][nt] = __builtin_amdgcn_mfma_f32_16x16x32_bf16(ah[mt], bh[nt], acc[mt][nt], 0, 0, 0);
                    acc[mt][nt] = __builtin_amdgcn_mfma_f32_16x16x32_bf16(ah[mt], bl[nt], acc[mt][nt], 0, 0, 0);
                    acc[mt][nt] = __builtin_amdgcn_mfma_f32_16x16x32_bf16(al[mt], bh[nt], acc[mt][nt], 0, 0, 0);
                }
        }
    }
    // ---- epilogue: atomic-add into xw; C/D layout col=lane&15, row=quad*4+reg ----
    #pragma unroll
    for (int mt = 0; mt < 2; ++mt)
        #pragma unroll
        for (int i = 0; i < 4; ++i) {
            int row = row0 + w * 32 + mt * 16 + quad * 4 + i;
            float* po = xw + (size_t)row * GC;
            atomicAdd(&po[l15], acc[mt][0][i]);
            atomicAdd(&po[16 + l15], acc[mt][1][i]);
        }
}

// ---------------- GCN gather (4-wide unrolled neighbor chain) ----------------
__global__ __launch_bounds__(256) void gcn_kernel(const float* __restrict__ xw,
                                                  const float* __restrict__ dis,
                                                  const unsigned* __restrict__ cnt,
                                                  const unsigned* __restrict__ offs,
                                                  const unsigned* __restrict__ adj,
                                                  const float* __restrict__ b1,
                                                  float* __restrict__ h) {
    int w = threadIdx.x >> 6;
    int lane = threadIdx.x & 63;
    int i = blockIdx.x * 4 + w;
    int f = lane & 31, half = lane >> 5;
    unsigned ci = cnt[i], oi = offs[i];
    float acc = 0.f;
    for (unsigned j = half; j < ci; j += 8) {
        unsigned lim = ci - 1;
        unsigned j1 = j + 2, j2 = j + 4, j3 = j + 6;
        unsigned d0 = adj[oi + j];
        unsigned d1 = adj[oi + min(j1, lim)];
        unsigned d2 = adj[oi + min(j2, lim)];
        unsigned d3 = adj[oi + min(j3, lim)];
        float m1 = j1 < ci ? 1.f : 0.f;
        float m2 = j2 < ci ? 1.f : 0.f;
        float m3 = j3 < ci ? 1.f : 0.f;
        acc += xw[(size_t)d0 * GC + f] * dis[d0];
        acc += m1 * xw[(size_t)d1 * GC + f] * dis[d1];
        acc += m2 * xw[(size_t)d2 * GC + f] * dis[d2];
        acc += m3 * xw[(size_t)d3 * GC + f] * dis[d3];
    }
    acc += __shfl_xor(acc, 32, 64);
    float disi = dis[i];
    float v = b1[f] + disi * (disi * xw[(size_t)i * GC + f] + acc);
    if (half == 0) h[(size_t)i * GC + f] = fmaxf(v, 0.f);
}

// ---------------- SAGE gather + fused head ----------------
__global__ __launch_bounds__(256) void sage_kernel(const float* __restrict__ h,
                                                   const unsigned* __restrict__ cnt,
                                                   const unsigned* __restrict__ offs,
                                                   const unsigned* __restrict__ adj,
                                                   const float* __restrict__ Wl,
                                                   const float* __restrict__ bl,
                                                   const float* __restrict__ Wr,
                                                   const float* __restrict__ br,
                                                   const float* __restrict__ W3,
                                                   const float* __restrict__ b3,
                                                   float* __restrict__ out) {
    __shared__ float sh[4][64];
    __shared__ float so[4][16];
    int w = threadIdx.x >> 6, lane = threadIdx.x & 63;
    int i = blockIdx.x * 4 + w;
    int f = lane & 31, half = lane >> 5;
    unsigned ci = cnt[i], oi = offs[i];
    float acc = 0.f;
    for (unsigned j = half; j < ci; j += 8) {
        unsigned lim = ci - 1;
        unsigned j1 = j + 2, j2 = j + 4, j3 = j + 6;
        unsigned d0 = adj[oi + j];
        unsigned d1 = adj[oi + min(j1, lim)];
        unsigned d2 = adj[oi + min(j2, lim)];
        unsigned d3 = adj[oi + min(j3, lim)];
        float m1 = j1 < ci ? 1.f : 0.f;
        float m2 = j2 < ci ? 1.f : 0.f;
        float m3 = j3 < ci ? 1.f : 0.f;
        acc += h[(size_t)d0 * GC + f];
        acc += m1 * h[(size_t)d1 * GC + f];
        acc += m2 * h[(size_t)d2 * GC + f];
        acc += m3 * h[(size_t)d3 * GC + f];
    }
    acc += __shfl_xor(acc, 32, 64);
    float agg = ci ? acc / (float)ci : 0.f;
    float hv = h[(size_t)i * GC + f];
    if (half == 0) { sh[w][f] = hv; sh[w][32 + f] = agg; }
    __syncthreads();
    int c = lane;
    float hid = 0.f;
    if (c < 16) {
        hid = bl[c] + br[c];
        #pragma unroll
        for (int ff = 0; ff < 32; ++ff)
            hid += sh[w][ff] * Wl[ff * 16 + c] + sh[w][32 + ff] * Wr[ff * 16 + c];
        hid = fmaxf(hid, 0.f);
    }
    float n2 = hid * hid;
    n2 += __shfl_xor(n2, 1, 64);
    n2 += __shfl_xor(n2, 2, 64);
    n2 += __shfl_xor(n2, 4, 64);
    n2 += __shfl_xor(n2, 8, 64);
    float o = hid / (sqrtf(n2) + 1e-6f);
    if (c < 16) so[w][c] = o;
    __syncthreads();
    float logit = -INFINITY;
    if (lane < 7) {
        logit = b3[lane];
        #pragma unroll
        for (int cc = 0; cc < 16; ++cc) logit += so[w][cc] * W3[cc * 7 + lane];
    }
    float m = logit;
    m = fmaxf(m, __shfl_xor(m, 1, 64));
    m = fmaxf(m, __shfl_xor(m, 2, 64));
    m = fmaxf(m, __shfl_xor(m, 4, 64));
    float e = expf(logit - m);
    float s = e;
    s += __shfl_xor(s, 1, 64);
    s += __shfl_xor(s, 2, 64);
    s += __shfl_xor(s, 4, 64);
    if (lane < 7) out[(size_t)i * 7 + lane] = e / s;
}

extern "C" void kernel_launch(void* const* d_in, const int* in_sizes, int n_in,
                              void* d_out, int out_size, void* d_ws, size_t ws_size,
                              hipStream_t stream) {
    const float* x  = (const float*)d_in[0];
    const int*   ei = (const int*)d_in[1];
    const float* W1 = (const float*)d_in[2];
    const float* b1 = (const float*)d_in[3];
    const float* Wl = (const float*)d_in[4];
    const float* bl = (const float*)d_in[5];
    const float* Wr = (const float*)d_in[6];
    const float* br = (const float*)d_in[7];
    const float* W3 = (const float*)d_in[8];
    const float* b3 = (const float*)d_in[9];
    float* out = (float*)d_out;

    const int nsplit = 12, kchunk = 128;  // 12*128 = 1536 >= 1433

    char* ws = (char*)d_ws;
    const size_t S = (size_t)GN * GC * 4;                 // 1.57 MB
    float*    xw      = (float*)(ws);
    float*    h       = (float*)(ws + S);
    float*    dis     = (float*)(ws + 2 * S);
    unsigned* deg     = (unsigned*)((char*)dis + (size_t)GN * 4);
    unsigned* cnt     = deg + GN;
    unsigned* cursor  = cnt + GN;
    unsigned* offs    = cursor + GN;
    unsigned* adj     = offs + GN;

    hipMemsetAsync(deg, 0, 3 * GN * sizeof(unsigned), stream);
    count_kernel<<<GE / 256, 256, 0, stream>>>(ei, deg, cnt, xw);
    prefix_kernel<<<1, 1024, 0, stream>>>(cnt, offs, deg, dis);
    scatter_kernel<<<GE / 256, 256, 0, stream>>>(ei, offs, cursor, adj);
    gemm_kernel<<<dim3(GN / 128, nsplit), 256, 0, stream>>>(x, W1, xw, kchunk);
    gcn_kernel<<<GN / 4, 256, 0, stream>>>(xw, dis, cnt, offs, adj, b1, h);
    sage_kernel<<<GN / 4, 256, 0, stream>>>(h, cnt, offs, adj, Wl, bl, Wr, br, W3, b3, out);
}